// Round 11
// baseline (171.476 us; speedup 1.0000x reference)
//
#include <hip/hip_runtime.h>
#include <stdint.h>
#include <stdio.h>

// ---------------------------------------------------------------------------
// Deterministic hard voxelization (mmcv hard_voxelize semantics), gfx950.
// d_out is FLOAT32: voxels[120000*35*4] | coors[120000*3] | npts[120000] |
// voxel_num[1] = 17,280,001 f32. Values bf16-RNE-rounded (matches expected).
//
// r11: TBITS 22 restored (r10's TBITS 21 doubled k_points: load factor 0.52
// -> 2.6 probes/insert vs 1.4; contended-atomic time ~ probe count, not table
// footprint). Keeps r10 tail (dupe-list + fused scanC fill + k_dupes).
// New: output-zero fused into k_sweep (read table || write zeros).
// ---------------------------------------------------------------------------

#define GXc 1408
#define GYc 1600
#define GXY (GXc * GYc)
#define MAXV 120000
#define MAXP 35
#define TBITS 22
#define TSIZE (1u << TBITS)
#define TMASK (TSIZE - 1u)
#define EMPTY64 0xFFFFFFFFFFFFFFFFull
#define INV32 0xFFFFFFFFu
#define SCAN_B 256
#define SCAN_I 8
#define SCAN_TILE (SCAN_B * SCAN_I)
#define OUT_ELEMS ((size_t)MAXV * MAXP * 4 + (size_t)MAXV * 3 + (size_t)MAXV + 1)

typedef unsigned long long u64;

__global__ void Voxelization_50345606644201_kernel() {}

__device__ __forceinline__ uint32_t mix32(uint32_t x) {
    x ^= x >> 16; x *= 0x85ebca6bu;
    x ^= x >> 13; x *= 0xc2b2ae35u;
    x ^= x >> 16;
    return x;
}

// f32 -> bf16-RNE -> f32
__device__ __forceinline__ float bfr(float f) {
    union { float f; uint32_t u; } v; v.f = f;
    v.u = (v.u + 0x7FFFu + ((v.u >> 16) & 1u)) & 0xFFFF0000u;
    return v.f;
}

struct Cell { int cx, cy, cz; int valid; };

// EXACT mirror of ref: c = floor((p - lo) / vsz); valid = all(0 <= c < grid)
__device__ __forceinline__ Cell cell_of(float4 p) {
    float fx = floorf((p.x - 0.0f)     / 0.05f);
    float fy = floorf((p.y - (-40.0f)) / 0.05f);
    float fz = floorf((p.z - (-3.0f))  / 0.1f);
    Cell c;
    c.valid = (fx >= 0.0f) && (fx < 1408.0f) &&
              (fy >= 0.0f) && (fy < 1600.0f) &&
              (fz >= 0.0f) && (fz < 40.0f);
    c.cx = (int)fx; c.cy = (int)fy; c.cz = (int)fz;
    return c;
}

// K1: init table + flags + cnt + ndupes
__global__ void k_init(u64* __restrict__ table, uint32_t* __restrict__ flags32,
                       uint32_t nfw, uint32_t* __restrict__ cnt,
                       uint32_t* __restrict__ ndupes) {
    uint32_t stride = gridDim.x * blockDim.x;
    uint32_t tid = blockIdx.x * blockDim.x + threadIdx.x;
    for (uint32_t j = tid; j < TSIZE; j += stride) table[j] = EMPTY64;
    for (uint32_t j = tid; j < nfw; j += stride) flags32[j] = 0u;
    for (uint32_t j = tid; j < (uint32_t)MAXV; j += stride) cnt[j] = 0u;
    if (tid == 0) *ndupes = 0u;
}

// K2: insert points (packed idx<<32|lin); per cell keep min idx; append exact
// dupe set (each same-cell collision resolves to one displaced-or-self idx)
__global__ void k_points(const float4* __restrict__ pts, int n,
                         u64* __restrict__ table,
                         uint32_t* __restrict__ dupes,
                         uint32_t* __restrict__ ndupes) {
    int i = blockIdx.x * blockDim.x + threadIdx.x;
    if (i >= n) return;
    float4 p = pts[i];
    Cell c = cell_of(p);
    if (!c.valid) return;
    uint32_t lin = (uint32_t)c.cz * (uint32_t)GXY
                 + (uint32_t)c.cy * (uint32_t)GXc + (uint32_t)c.cx;
    u64 val = ((u64)(uint32_t)i << 32) | (u64)lin;
    uint32_t h = mix32(lin) & TMASK;
    for (uint32_t probes = 0; probes <= TMASK; probes++) {
        u64 prev = atomicCAS(&table[h], EMPTY64, val);
        if (prev == EMPTY64) return;                 // claimed slot for this cell
        if ((uint32_t)prev == lin) {                 // same cell: min-idx contest
            u64 old = atomicMin(&table[h], val);
            uint32_t dup = (val < old) ? (uint32_t)(old >> 32) : (uint32_t)i;
            uint32_t k = atomicAdd(ndupes, 1u);
            dupes[k] = dup;
            return;
        }
        h = (h + 1u) & TMASK;
    }
}

// K3: coalesced table sweep -> flags[minidx]=1; FUSED: zero the f32 output
__global__ void k_sweep_zero(const u64* __restrict__ table,
                             uint8_t* __restrict__ flags,
                             float4* __restrict__ o4,
                             float* __restrict__ out) {
    uint32_t stride = gridDim.x * blockDim.x;
    uint32_t tid = blockIdx.x * blockDim.x + threadIdx.x;
    for (uint32_t j = tid; j < TSIZE; j += stride) {
        u64 e = table[j];
        if (e != EMPTY64) flags[(uint32_t)(e >> 32)] = 1u;
    }
    const size_t nq = OUT_ELEMS / 4;                 // 4,320,000 float4s
    float4 z = make_float4(0.f, 0.f, 0.f, 0.f);
    for (size_t j = tid; j < nq; j += stride)
        o4[j] = z;
    if (tid == 0) out[OUT_ELEMS - 1] = 0.0f;
}

__device__ __forceinline__ uint32_t flag_at(const uint8_t* __restrict__ flags,
                                            int i, int n) {
    return (i < n) ? (uint32_t)flags[i] : 0u;
}

// K4: per-block sums of rep flags
__global__ void k_scanA(const uint8_t* __restrict__ flags, int n,
                        uint32_t* __restrict__ bsums) {
    __shared__ uint32_t sh[SCAN_B];
    int t = threadIdx.x;
    int myStart = blockIdx.x * SCAN_TILE + t * SCAN_I;
    uint32_t s = 0;
    #pragma unroll
    for (int j = 0; j < SCAN_I; j++) s += flag_at(flags, myStart + j, n);
    sh[t] = s; __syncthreads();
    for (int off = SCAN_B / 2; off > 0; off >>= 1) {
        if (t < off) sh[t] += sh[t + off];
        __syncthreads();
    }
    if (t == 0) bsums[blockIdx.x] = sh[0];
}

// K5: exclusive scan of <=1024 block sums; writes tot + voxel_num
__global__ void k_scanB(uint32_t* __restrict__ bsums, int nb,
                        uint32_t* __restrict__ tot,
                        float* __restrict__ voxnum) {
    __shared__ uint32_t sh[SCAN_B];
    int t = threadIdx.x;
    uint32_t v[4]; uint32_t s = 0;
    #pragma unroll
    for (int j = 0; j < 4; j++) {
        int idx = t * 4 + j;
        v[j] = (idx < nb) ? bsums[idx] : 0u;
        s += v[j];
    }
    sh[t] = s; __syncthreads();
    for (int off = 1; off < SCAN_B; off <<= 1) {
        uint32_t add = (t >= off) ? sh[t - off] : 0u;
        __syncthreads();
        sh[t] += add;
        __syncthreads();
    }
    uint32_t ex = sh[t] - s;
    #pragma unroll
    for (int j = 0; j < 4; j++) {
        int idx = t * 4 + j;
        if (idx < nb) bsums[idx] = ex;
        ex += v[j];
    }
    if (t == SCAN_B - 1) {
        uint32_t total = sh[SCAN_B - 1];
        *tot = total;
        uint32_t vn = total < (uint32_t)MAXV ? total : (uint32_t)MAXV;
        *voxnum = bfr((float)vn);
    }
}

// K6: rescan flags; assign ranks; write vrank; for rank<MAXV fill slot 0
// (rep = min index of its cell -> always ends at slot 0 after k_final sort),
// plus coors and cnt=1. Only reps with rank<MAXV read pts (~first 167K).
__global__ void k_scanC(const float4* __restrict__ pts,
                        const uint8_t* __restrict__ flags, int n,
                        const uint32_t* __restrict__ boffs,
                        uint32_t* __restrict__ vrank,
                        float* __restrict__ coors,
                        uint32_t* __restrict__ cnt,
                        uint32_t* __restrict__ slotsrc,
                        float4* __restrict__ vox4) {
    __shared__ uint32_t sh[SCAN_B];
    int t = threadIdx.x;
    int myStart = blockIdx.x * SCAN_TILE + t * SCAN_I;
    uint32_t f[SCAN_I];
    uint32_t lsum = 0;
    #pragma unroll
    for (int j = 0; j < SCAN_I; j++) {
        f[j] = flag_at(flags, myStart + j, n);
        lsum += f[j];
    }
    sh[t] = lsum; __syncthreads();
    for (int off = 1; off < SCAN_B; off <<= 1) {
        uint32_t add = (t >= off) ? sh[t - off] : 0u;
        __syncthreads();
        sh[t] += add;
        __syncthreads();
    }
    uint32_t rank = boffs[blockIdx.x] + (sh[t] - lsum);
    for (int j = 0; j < SCAN_I; j++) {
        if (f[j]) {
            int i = myStart + j;
            if (rank < (uint32_t)MAXV) {
                vrank[i] = rank;
                float4 p = pts[i];
                Cell c = cell_of(p);
                size_t cb = (size_t)rank * 3;
                coors[cb + 0] = bfr((float)c.cz);   // mmcv order (z, y, x)
                coors[cb + 1] = bfr((float)c.cy);
                coors[cb + 2] = bfr((float)c.cx);
                uint32_t base = rank * (uint32_t)MAXP;
                cnt[rank] = 1u;
                slotsrc[base] = (uint32_t)i;
                vox4[base] = make_float4(bfr(p.x), bfr(p.y), bfr(p.z), bfr(p.w));
            } else {
                vrank[i] = INV32;
            }
            rank++;
        }
    }
}

// K7: fill dupes (~7K): re-probe table for cell rep, append to slots 1+
__global__ void k_dupes(const float4* __restrict__ pts,
                        const u64* __restrict__ table,
                        const uint32_t* __restrict__ vrank,
                        const uint32_t* __restrict__ dupes,
                        const uint32_t* __restrict__ ndupes,
                        uint32_t* __restrict__ cnt,
                        uint32_t* __restrict__ slotsrc,
                        float4* __restrict__ vox4) {
    uint32_t nd = *ndupes;
    uint32_t stride = gridDim.x * blockDim.x;
    for (uint32_t j = blockIdx.x * blockDim.x + threadIdx.x; j < nd; j += stride) {
        uint32_t i = dupes[j];
        float4 p = pts[i];
        Cell c = cell_of(p);
        uint32_t lin = (uint32_t)c.cz * (uint32_t)GXY
                     + (uint32_t)c.cy * (uint32_t)GXc + (uint32_t)c.cx;
        uint32_t h = mix32(lin) & TMASK;
        uint32_t mi = INV32;
        for (uint32_t probes = 0; probes <= TMASK; probes++) {
            u64 e = table[h];
            if ((uint32_t)e == lin) { mi = (uint32_t)(e >> 32); break; }
            if (e == EMPTY64) break;
            h = (h + 1u) & TMASK;
        }
        if (mi == INV32) continue;
        uint32_t v = vrank[mi];
        if (v >= (uint32_t)MAXV) continue;
        uint32_t s = atomicAdd(&cnt[v], 1u);
        if (s < (uint32_t)MAXP) {
            uint32_t idx = v * (uint32_t)MAXP + s;
            slotsrc[idx] = i;
            vox4[idx] = make_float4(bfr(p.x), bfr(p.y), bfr(p.z), bfr(p.w));
        }
    }
}

// K8: npts = min(cnt,35); restore original-index slot order; rewrite voxnum
__global__ void k_final(const uint32_t* __restrict__ cnt,
                        uint32_t* __restrict__ slotsrc,
                        float4* __restrict__ vox4,
                        float* __restrict__ npts,
                        const uint32_t* __restrict__ tot,
                        float* __restrict__ voxnum) {
    int v = blockIdx.x * blockDim.x + threadIdx.x;
    if (blockIdx.x == 0 && threadIdx.x == 0) {
        uint32_t total = *tot;
        uint32_t vn = total < (uint32_t)MAXV ? total : (uint32_t)MAXV;
        *voxnum = bfr((float)vn);
    }
    if (v >= MAXV) return;
    uint32_t c = cnt[v];
    uint32_t m = c < (uint32_t)MAXP ? c : (uint32_t)MAXP;
    npts[v] = bfr((float)m);
    if (m >= 2u) {
        uint32_t base = (uint32_t)v * (uint32_t)MAXP;
        for (uint32_t a = 0; a + 1u < m; a++) {
            uint32_t best = a, bi = slotsrc[base + a];
            for (uint32_t b = a + 1u; b < m; b++) {
                uint32_t ti = slotsrc[base + b];
                if (ti < bi) { bi = ti; best = b; }
            }
            if (best != a) {
                uint32_t ta = slotsrc[base + a];
                slotsrc[base + a] = slotsrc[base + best];
                slotsrc[base + best] = ta;
                float4 va = vox4[base + a];
                vox4[base + a] = vox4[base + best];
                vox4[base + best] = va;
            }
        }
    }
}

extern "C" void kernel_launch(void* const* d_in, const int* in_sizes, int n_in,
                              void* d_out, int out_size, void* d_ws, size_t ws_size,
                              hipStream_t stream) {
    (void)n_in; (void)out_size;
    const float4* pts = (const float4*)d_in[0];
    int n = in_sizes[0] / 4;

    float* out    = (float*)d_out;
    float* coors  = out + (size_t)MAXV * MAXP * 4;
    float* npts   = coors + (size_t)MAXV * 3;
    float* voxnum = out + (OUT_ELEMS - 1);

    // ---- workspace layout ----
    size_t off = 0;
    size_t oT = off;  off += (size_t)TSIZE * 8;                // table (32MB)
    size_t oF = off;  off += ((size_t)n + 255) & ~(size_t)255; // flags u8
    size_t oV = off;  off += (size_t)n * 4;                    // vrank
    size_t oD = off;  off += (size_t)n * 4;                    // dupes
    off = (off + 255) & ~(size_t)255;
    size_t oC = off;  off += (size_t)MAXV * 4;                 // cnt
    off = (off + 255) & ~(size_t)255;
    size_t oB = off;  off += 4096;                             // bsums
    size_t oX = off;  off += 256;                              // tot + ndupes
    size_t oS = off;  off += (size_t)MAXV * MAXP * 4;          // slotsrc
    size_t need = off;

    if (need > ws_size) {                     // ~75MB vs 276MB: never expected
        k_sweep_zero<<<2048, 256, 0, stream>>>((u64*)d_ws, (uint8_t*)d_ws,
                                               (float4*)d_out, out);
        return;
    }

    char* w = (char*)d_ws;
    u64*      table   = (u64*)(w + oT);
    uint8_t*  flags   = (uint8_t*)(w + oF);
    uint32_t* vrank   = (uint32_t*)(w + oV);
    uint32_t* dupes   = (uint32_t*)(w + oD);
    uint32_t* cnt     = (uint32_t*)(w + oC);
    uint32_t* bsums   = (uint32_t*)(w + oB);
    uint32_t* tot     = (uint32_t*)(w + oX);
    uint32_t* ndupes  = (uint32_t*)(w + oX) + 1;
    uint32_t* slotsrc = (uint32_t*)(w + oS);

    int nbPts  = (n + 255) / 256;
    int nbScan = (n + SCAN_TILE - 1) / SCAN_TILE;   // 733 (<=1024)
    uint32_t nfw = ((uint32_t)n + 3u) / 4u;

    k_init<<<2048, 256, 0, stream>>>(table, (uint32_t*)flags, nfw, cnt, ndupes);
    k_points<<<nbPts, 256, 0, stream>>>(pts, n, table, dupes, ndupes);
    k_sweep_zero<<<2048, 256, 0, stream>>>(table, flags, (float4*)d_out, out);
    k_scanA<<<nbScan, SCAN_B, 0, stream>>>(flags, n, bsums);
    k_scanB<<<1, SCAN_B, 0, stream>>>(bsums, nbScan, tot, voxnum);
    k_scanC<<<nbScan, SCAN_B, 0, stream>>>(pts, flags, n, bsums, vrank, coors,
                                           cnt, slotsrc, (float4*)out);
    k_dupes<<<128, 256, 0, stream>>>(pts, table, vrank, dupes, ndupes,
                                     cnt, slotsrc, (float4*)out);
    k_final<<<(MAXV + 255) / 256, 256, 0, stream>>>(cnt, slotsrc, (float4*)out,
                                                    npts, tot, voxnum);

    // slim telemetry on the non-captured (correctness) call only
    hipStreamCaptureStatus cs = hipStreamCaptureStatusNone;
    (void)hipStreamIsCapturing(stream, &cs);
    if (cs == hipStreamCaptureStatusNone) {
        static uint32_t h_tot, h_nd; static float h_vn;
        h_tot = 0; h_nd = 0; h_vn = -1.0f;
        (void)hipStreamSynchronize(stream);
        (void)hipMemcpyAsync(&h_tot, tot, 4, hipMemcpyDeviceToHost, stream);
        (void)hipMemcpyAsync(&h_nd, ndupes, 4, hipMemcpyDeviceToHost, stream);
        (void)hipMemcpyAsync(&h_vn, voxnum, 4, hipMemcpyDeviceToHost, stream);
        (void)hipStreamSynchronize(stream);
        fprintf(stderr, "[vox r11] n=%d tot=%u ndupes=%u voxnum=%.1f (exp 119808)\n",
                n, h_tot, h_nd, h_vn);
        fflush(stderr);
    }
}

// Round 12
// 86.902 us; speedup vs baseline: 1.9732x; 1.9732x over previous
//
#include <hip/hip_runtime.h>
#include <stdint.h>
#include <stdio.h>

// ---------------------------------------------------------------------------
// Deterministic hard voxelization (mmcv hard_voxelize semantics), gfx950.
// d_out is FLOAT32: voxels[120000*35*4] | coors[120000*3] | npts[120000] |
// voxel_num[1] = 17,280,001 f32. Values bf16-RNE-rounded (matches expected).
//
// r12: (a) dupe capture via scattered dupeflag bytes (r10/r11's single-line
// ndupes atomicAdd cost ~60us of serialized queue: ~9ns per same-address op);
// (b) prefix-split: full CAS insert only for [0,M); later points do READ-ONLY
// probes when prefix already holds >=MAXV distinct cells (ranks are monotone
// in rep index, so absent cells would rank >=MAXV -> dropped). Guarded
// fallback keeps exact semantics for arbitrary inputs.
// ---------------------------------------------------------------------------

#define GXc 1408
#define GYc 1600
#define GXY (GXc * GYc)
#define MAXV 120000
#define MAXP 35
#define MPREFIX 262144
#define TBITS 22
#define TSIZE (1u << TBITS)
#define TMASK (TSIZE - 1u)
#define EMPTY64 0xFFFFFFFFFFFFFFFFull
#define INV32 0xFFFFFFFFu
#define SCAN_B 256
#define SCAN_I 8
#define SCAN_TILE (SCAN_B * SCAN_I)
#define OUT_ELEMS ((size_t)MAXV * MAXP * 4 + (size_t)MAXV * 3 + (size_t)MAXV + 1)

typedef unsigned long long u64;

__global__ void Voxelization_50345606644201_kernel() {}

__device__ __forceinline__ uint32_t mix32(uint32_t x) {
    x ^= x >> 16; x *= 0x85ebca6bu;
    x ^= x >> 13; x *= 0xc2b2ae35u;
    x ^= x >> 16;
    return x;
}

// f32 -> bf16-RNE -> f32
__device__ __forceinline__ float bfr(float f) {
    union { float f; uint32_t u; } v; v.f = f;
    v.u = (v.u + 0x7FFFu + ((v.u >> 16) & 1u)) & 0xFFFF0000u;
    return v.f;
}

struct Cell { int cx, cy, cz; int valid; };

// EXACT mirror of ref: c = floor((p - lo) / vsz); valid = all(0 <= c < grid)
__device__ __forceinline__ Cell cell_of(float4 p) {
    float fx = floorf((p.x - 0.0f)     / 0.05f);
    float fy = floorf((p.y - (-40.0f)) / 0.05f);
    float fz = floorf((p.z - (-3.0f))  / 0.1f);
    Cell c;
    c.valid = (fx >= 0.0f) && (fx < 1408.0f) &&
              (fy >= 0.0f) && (fy < 1600.0f) &&
              (fz >= 0.0f) && (fz < 40.0f);
    c.cx = (int)fx; c.cy = (int)fy; c.cz = (int)fz;
    return c;
}

// K1: init table + flags + dupeflag + cnt + counters
__global__ void k_init(u64* __restrict__ table, uint32_t* __restrict__ flags32,
                       uint32_t* __restrict__ dupeflag32, uint32_t nfw,
                       uint32_t* __restrict__ cnt, uint32_t* __restrict__ misc) {
    uint32_t stride = gridDim.x * blockDim.x;
    uint32_t tid = blockIdx.x * blockDim.x + threadIdx.x;
    for (uint32_t j = tid; j < TSIZE; j += stride) table[j] = EMPTY64;
    for (uint32_t j = tid; j < nfw; j += stride) { flags32[j] = 0u; dupeflag32[j] = 0u; }
    for (uint32_t j = tid; j < (uint32_t)MAXV; j += stride) cnt[j] = 0u;
    if (tid == 0) { misc[0] = 0u; misc[1] = 0u; }   // tot, gclaims
}

// K2a: full insert for prefix [0, M); per-block LDS claim count -> gclaims
__global__ void k_pointsA(const float4* __restrict__ pts, int M,
                          u64* __restrict__ table,
                          uint8_t* __restrict__ dupeflag,
                          uint32_t* __restrict__ gclaims) {
    __shared__ uint32_t scl;
    if (threadIdx.x == 0) scl = 0u;
    __syncthreads();
    uint32_t claims = 0;
    int base = blockIdx.x * (blockDim.x * 4) + threadIdx.x;
    #pragma unroll
    for (int r = 0; r < 4; r++) {
        int i = base + r * blockDim.x;               // coalesced
        if (i < M) {
            float4 p = pts[i];
            Cell c = cell_of(p);
            if (c.valid) {
                uint32_t lin = (uint32_t)c.cz * (uint32_t)GXY
                             + (uint32_t)c.cy * (uint32_t)GXc + (uint32_t)c.cx;
                u64 val = ((u64)(uint32_t)i << 32) | (u64)lin;
                uint32_t h = mix32(lin) & TMASK;
                for (uint32_t probes = 0; probes <= TMASK; probes++) {
                    u64 prev = atomicCAS(&table[h], EMPTY64, val);
                    if (prev == EMPTY64) { claims++; break; }
                    if ((uint32_t)prev == lin) {     // same-cell min-idx contest
                        u64 old = atomicMin(&table[h], val);
                        uint32_t loser = (val < old) ? (uint32_t)(old >> 32)
                                                     : (uint32_t)i;
                        dupeflag[loser] = 1u;        // scattered u8, no hot line
                        break;
                    }
                    h = (h + 1u) & TMASK;
                }
            }
        }
    }
    if (claims) atomicAdd(&scl, claims);
    __syncthreads();
    if (threadIdx.x == 0 && scl) atomicAdd(gclaims, scl);
}

// K2b: points [M, n). If prefix holds >=MAXV distinct cells: read-only probe
// (present -> dupe, absent -> would rank >=MAXV -> drop). Else: full insert.
__global__ void k_pointsB(const float4* __restrict__ pts, int M, int n,
                          u64* __restrict__ table,
                          uint8_t* __restrict__ dupeflag,
                          const uint32_t* __restrict__ gclaims) {
    int i = M + blockIdx.x * blockDim.x + threadIdx.x;
    if (i >= n) return;
    float4 p = pts[i];
    Cell c = cell_of(p);
    if (!c.valid) return;
    uint32_t lin = (uint32_t)c.cz * (uint32_t)GXY
                 + (uint32_t)c.cy * (uint32_t)GXc + (uint32_t)c.cx;
    u64 val = ((u64)(uint32_t)i << 32) | (u64)lin;
    const bool doIns = (*gclaims < (uint32_t)MAXV);  // uniform scalar
    uint32_t h = mix32(lin) & TMASK;
    for (uint32_t probes = 0; probes <= TMASK; probes++) {
        u64 e = table[h];                            // plain read (clean line)
        if ((uint32_t)e == lin) { dupeflag[i] = 1u; return; }   // lin != 0xFFFFFFFF
        if (e == EMPTY64) {
            if (!doIns) return;                      // drop: rank would be >= MAXV
            u64 prev = atomicCAS(&table[h], EMPTY64, val);
            if (prev == EMPTY64) return;             // inserted
            if ((uint32_t)prev == lin) {
                u64 old = atomicMin(&table[h], val);
                uint32_t loser = (val < old) ? (uint32_t)(old >> 32) : (uint32_t)i;
                dupeflag[loser] = 1u;
                return;
            }
            // other cell won this slot; fall through to next probe
        }
        h = (h + 1u) & TMASK;
    }
}

// K3: coalesced table sweep -> flags[repidx]=1; FUSED: zero the f32 output
__global__ void k_sweep_zero(const u64* __restrict__ table,
                             uint8_t* __restrict__ flags,
                             float4* __restrict__ o4,
                             float* __restrict__ out) {
    uint32_t stride = gridDim.x * blockDim.x;
    uint32_t tid = blockIdx.x * blockDim.x + threadIdx.x;
    for (uint32_t j = tid; j < TSIZE; j += stride) {
        u64 e = table[j];
        if (e != EMPTY64) flags[(uint32_t)(e >> 32)] = 1u;
    }
    const size_t nq = OUT_ELEMS / 4;
    float4 z = make_float4(0.f, 0.f, 0.f, 0.f);
    for (size_t j = tid; j < nq; j += stride) o4[j] = z;
    if (tid == 0) out[OUT_ELEMS - 1] = 0.0f;
}

__device__ __forceinline__ uint32_t flag_at(const uint8_t* __restrict__ flags,
                                            int i, int n) {
    return (i < n) ? (uint32_t)flags[i] : 0u;
}

// K4: per-block sums of rep flags
__global__ void k_scanA(const uint8_t* __restrict__ flags, int n,
                        uint32_t* __restrict__ bsums) {
    __shared__ uint32_t sh[SCAN_B];
    int t = threadIdx.x;
    int myStart = blockIdx.x * SCAN_TILE + t * SCAN_I;
    uint32_t s = 0;
    #pragma unroll
    for (int j = 0; j < SCAN_I; j++) s += flag_at(flags, myStart + j, n);
    sh[t] = s; __syncthreads();
    for (int off = SCAN_B / 2; off > 0; off >>= 1) {
        if (t < off) sh[t] += sh[t + off];
        __syncthreads();
    }
    if (t == 0) bsums[blockIdx.x] = sh[0];
}

// K5: exclusive scan of <=1024 block sums; writes tot + voxel_num
__global__ void k_scanB(uint32_t* __restrict__ bsums, int nb,
                        uint32_t* __restrict__ tot,
                        float* __restrict__ voxnum) {
    __shared__ uint32_t sh[SCAN_B];
    int t = threadIdx.x;
    uint32_t v[4]; uint32_t s = 0;
    #pragma unroll
    for (int j = 0; j < 4; j++) {
        int idx = t * 4 + j;
        v[j] = (idx < nb) ? bsums[idx] : 0u;
        s += v[j];
    }
    sh[t] = s; __syncthreads();
    for (int off = 1; off < SCAN_B; off <<= 1) {
        uint32_t add = (t >= off) ? sh[t - off] : 0u;
        __syncthreads();
        sh[t] += add;
        __syncthreads();
    }
    uint32_t ex = sh[t] - s;
    #pragma unroll
    for (int j = 0; j < 4; j++) {
        int idx = t * 4 + j;
        if (idx < nb) bsums[idx] = ex;
        ex += v[j];
    }
    if (t == SCAN_B - 1) {
        uint32_t total = sh[SCAN_B - 1];
        *tot = total;
        uint32_t vn = total < (uint32_t)MAXV ? total : (uint32_t)MAXV;
        *voxnum = bfr((float)vn);
    }
}

// K6: rescan flags; assign ranks; write vrank; for rank<MAXV fill slot 0
// plus coors and cnt=1 (rep = min index -> ends at slot 0 after k_final sort)
__global__ void k_scanC(const float4* __restrict__ pts,
                        const uint8_t* __restrict__ flags, int n,
                        const uint32_t* __restrict__ boffs,
                        uint32_t* __restrict__ vrank,
                        float* __restrict__ coors,
                        uint32_t* __restrict__ cnt,
                        uint32_t* __restrict__ slotsrc,
                        float4* __restrict__ vox4) {
    __shared__ uint32_t sh[SCAN_B];
    int t = threadIdx.x;
    int myStart = blockIdx.x * SCAN_TILE + t * SCAN_I;
    uint32_t f[SCAN_I];
    uint32_t lsum = 0;
    #pragma unroll
    for (int j = 0; j < SCAN_I; j++) {
        f[j] = flag_at(flags, myStart + j, n);
        lsum += f[j];
    }
    sh[t] = lsum; __syncthreads();
    for (int off = 1; off < SCAN_B; off <<= 1) {
        uint32_t add = (t >= off) ? sh[t - off] : 0u;
        __syncthreads();
        sh[t] += add;
        __syncthreads();
    }
    uint32_t rank = boffs[blockIdx.x] + (sh[t] - lsum);
    for (int j = 0; j < SCAN_I; j++) {
        if (f[j]) {
            int i = myStart + j;
            if (rank < (uint32_t)MAXV) {
                vrank[i] = rank;
                float4 p = pts[i];
                Cell c = cell_of(p);
                size_t cb = (size_t)rank * 3;
                coors[cb + 0] = bfr((float)c.cz);   // mmcv order (z, y, x)
                coors[cb + 1] = bfr((float)c.cy);
                coors[cb + 2] = bfr((float)c.cx);
                uint32_t base = rank * (uint32_t)MAXP;
                cnt[rank] = 1u;
                slotsrc[base] = (uint32_t)i;
                vox4[base] = make_float4(bfr(p.x), bfr(p.y), bfr(p.z), bfr(p.w));
            } else {
                vrank[i] = INV32;
            }
            rank++;
        }
    }
}

// K7: sweep dupeflag; each dupe re-probes table for its rep, appends slot 1+
__global__ void k_dupes(const float4* __restrict__ pts,
                        const u64* __restrict__ table,
                        const uint32_t* __restrict__ vrank,
                        const uint8_t* __restrict__ dupeflag, int n,
                        uint32_t* __restrict__ cnt,
                        uint32_t* __restrict__ slotsrc,
                        float4* __restrict__ vox4) {
    int stride = gridDim.x * blockDim.x;
    for (int i = blockIdx.x * blockDim.x + threadIdx.x; i < n; i += stride) {
        if (!dupeflag[i]) continue;
        float4 p = pts[i];
        Cell c = cell_of(p);
        uint32_t lin = (uint32_t)c.cz * (uint32_t)GXY
                     + (uint32_t)c.cy * (uint32_t)GXc + (uint32_t)c.cx;
        uint32_t h = mix32(lin) & TMASK;
        uint32_t mi = INV32;
        for (uint32_t probes = 0; probes <= TMASK; probes++) {
            u64 e = table[h];
            if ((uint32_t)e == lin) { mi = (uint32_t)(e >> 32); break; }
            if (e == EMPTY64) break;
            h = (h + 1u) & TMASK;
        }
        if (mi == INV32) continue;
        uint32_t v = vrank[mi];
        if (v >= (uint32_t)MAXV) continue;
        uint32_t s = atomicAdd(&cnt[v], 1u);
        if (s < (uint32_t)MAXP) {
            uint32_t idx = v * (uint32_t)MAXP + s;
            slotsrc[idx] = (uint32_t)i;
            vox4[idx] = make_float4(bfr(p.x), bfr(p.y), bfr(p.z), bfr(p.w));
        }
    }
}

// K8: npts = min(cnt,35); restore original-index slot order; rewrite voxnum
__global__ void k_final(const uint32_t* __restrict__ cnt,
                        uint32_t* __restrict__ slotsrc,
                        float4* __restrict__ vox4,
                        float* __restrict__ npts,
                        const uint32_t* __restrict__ tot,
                        float* __restrict__ voxnum) {
    int v = blockIdx.x * blockDim.x + threadIdx.x;
    if (blockIdx.x == 0 && threadIdx.x == 0) {
        uint32_t total = *tot;
        uint32_t vn = total < (uint32_t)MAXV ? total : (uint32_t)MAXV;
        *voxnum = bfr((float)vn);
    }
    if (v >= MAXV) return;
    uint32_t c = cnt[v];
    uint32_t m = c < (uint32_t)MAXP ? c : (uint32_t)MAXP;
    npts[v] = bfr((float)m);
    if (m >= 2u) {
        uint32_t base = (uint32_t)v * (uint32_t)MAXP;
        for (uint32_t a = 0; a + 1u < m; a++) {
            uint32_t best = a, bi = slotsrc[base + a];
            for (uint32_t b = a + 1u; b < m; b++) {
                uint32_t ti = slotsrc[base + b];
                if (ti < bi) { bi = ti; best = b; }
            }
            if (best != a) {
                uint32_t ta = slotsrc[base + a];
                slotsrc[base + a] = slotsrc[base + best];
                slotsrc[base + best] = ta;
                float4 va = vox4[base + a];
                vox4[base + a] = vox4[base + best];
                vox4[base + best] = va;
            }
        }
    }
}

extern "C" void kernel_launch(void* const* d_in, const int* in_sizes, int n_in,
                              void* d_out, int out_size, void* d_ws, size_t ws_size,
                              hipStream_t stream) {
    (void)n_in; (void)out_size;
    const float4* pts = (const float4*)d_in[0];
    int n = in_sizes[0] / 4;
    int M = MPREFIX < n ? MPREFIX : n;

    float* out    = (float*)d_out;
    float* coors  = out + (size_t)MAXV * MAXP * 4;
    float* npts   = coors + (size_t)MAXV * 3;
    float* voxnum = out + (OUT_ELEMS - 1);

    // ---- workspace layout ----
    size_t npad = ((size_t)n + 255) & ~(size_t)255;
    size_t off = 0;
    size_t oT = off;  off += (size_t)TSIZE * 8;        // table (32MB)
    size_t oF = off;  off += npad;                     // flags u8
    size_t oDF = off; off += npad;                     // dupeflag u8
    size_t oV = off;  off += (size_t)n * 4;            // vrank
    off = (off + 255) & ~(size_t)255;
    size_t oC = off;  off += (size_t)MAXV * 4;         // cnt
    off = (off + 255) & ~(size_t)255;
    size_t oB = off;  off += 4096;                     // bsums
    size_t oX = off;  off += 256;                      // misc: tot, gclaims
    size_t oS = off;  off += (size_t)MAXV * MAXP * 4;  // slotsrc
    size_t need = off;

    if (need > ws_size) {                              // ~60MB vs 276MB
        k_sweep_zero<<<2048, 256, 0, stream>>>((u64*)d_ws, (uint8_t*)d_ws,
                                               (float4*)d_out, out);
        return;
    }

    char* w = (char*)d_ws;
    u64*      table    = (u64*)(w + oT);
    uint8_t*  flags    = (uint8_t*)(w + oF);
    uint8_t*  dupeflag = (uint8_t*)(w + oDF);
    uint32_t* vrank    = (uint32_t*)(w + oV);
    uint32_t* cnt      = (uint32_t*)(w + oC);
    uint32_t* bsums    = (uint32_t*)(w + oB);
    uint32_t* misc     = (uint32_t*)(w + oX);
    uint32_t* tot      = misc;
    uint32_t* gclaims  = misc + 1;
    uint32_t* slotsrc  = (uint32_t*)(w + oS);

    int nbA    = (M + 1023) / 1024;                    // 4 pts/thread
    int nbB    = (n - M + 255) / 256;
    int nbScan = (n + SCAN_TILE - 1) / SCAN_TILE;      // 733 (<=1024)
    uint32_t nfw = ((uint32_t)npad) / 4u;

    k_init<<<2048, 256, 0, stream>>>(table, (uint32_t*)flags,
                                     (uint32_t*)dupeflag, nfw, cnt, misc);
    k_pointsA<<<nbA, 256, 0, stream>>>(pts, M, table, dupeflag, gclaims);
    if (n > M)
        k_pointsB<<<nbB, 256, 0, stream>>>(pts, M, n, table, dupeflag, gclaims);
    k_sweep_zero<<<2048, 256, 0, stream>>>(table, flags, (float4*)d_out, out);
    k_scanA<<<nbScan, SCAN_B, 0, stream>>>(flags, n, bsums);
    k_scanB<<<1, SCAN_B, 0, stream>>>(bsums, nbScan, tot, voxnum);
    k_scanC<<<nbScan, SCAN_B, 0, stream>>>(pts, flags, n, bsums, vrank, coors,
                                           cnt, slotsrc, (float4*)out);
    k_dupes<<<1024, 256, 0, stream>>>(pts, table, vrank, dupeflag, n,
                                      cnt, slotsrc, (float4*)out);
    k_final<<<(MAXV + 255) / 256, 256, 0, stream>>>(cnt, slotsrc, (float4*)out,
                                                    npts, tot, voxnum);

    // slim telemetry on the non-captured (correctness) call only
    hipStreamCaptureStatus cs = hipStreamCaptureStatusNone;
    (void)hipStreamIsCapturing(stream, &cs);
    if (cs == hipStreamCaptureStatusNone) {
        static uint32_t h_tot, h_cl; static float h_vn;
        h_tot = 0; h_cl = 0; h_vn = -1.0f;
        (void)hipStreamSynchronize(stream);
        (void)hipMemcpyAsync(&h_tot, tot, 4, hipMemcpyDeviceToHost, stream);
        (void)hipMemcpyAsync(&h_cl, gclaims, 4, hipMemcpyDeviceToHost, stream);
        (void)hipMemcpyAsync(&h_vn, voxnum, 4, hipMemcpyDeviceToHost, stream);
        (void)hipStreamSynchronize(stream);
        fprintf(stderr, "[vox r12] n=%d M=%d claims=%u tot=%u voxnum=%.1f (exp 119808)\n",
                n, M, h_cl, h_tot, h_vn);
        fflush(stderr);
    }
}